// Round 2
// baseline (284.907 us; speedup 1.0000x reference)
//
#include <hip/hip_runtime.h>
#include <hip/hip_bf16.h>
#include <cmath>

#define BB 2
#define TT 64
#define CC 384
#define HH 768

// d_out flat offsets (fp32 elements): out, nW0, nb0, nW1, nb1
#define O_OUT 0
#define O_NW0 768
#define O_NB0 (768 + 589824)
#define O_NW1 (O_NB0 + 1536)
#define O_NB1 (O_NW1 + 589824)

#define GRID_BLKS 312

struct Coefs { float ct[TT]; float dfac; };

typedef __attribute__((ext_vector_type(8))) short bf16x8;
typedef __attribute__((ext_vector_type(4))) float f32x4;

__device__ __forceinline__ float bf2f(unsigned short u) {
    union { unsigned int i; float f; } x; x.i = ((unsigned int)u) << 16; return x.f;
}
__device__ __forceinline__ unsigned short f2bf(float f) {
    union { float f; unsigned int i; } u; u.f = f;
    unsigned int x = u.i;
    unsigned int r = (x + 0x7fffu + ((x >> 16) & 1u)) >> 16;  // RNE
    return (unsigned short)r;
}
__device__ __forceinline__ f32x4 mfma16(bf16x8 a, bf16x8 b, f32x4 c) {
    return __builtin_amdgcn_mfma_f32_16x16x32_bf16(a, b, c, 0, 0, 0);
}
__device__ __forceinline__ bf16x8 ldbf8(const unsigned short* p) {
    return *(const bf16x8*)p;
}
__device__ __forceinline__ bf16x8 ldcvt8(const float* p) {
    float4 a = *(const float4*)p, b = *(const float4*)(p + 4);
    bf16x8 r;
    r[0] = (short)f2bf(a.x); r[1] = (short)f2bf(a.y); r[2] = (short)f2bf(a.z); r[3] = (short)f2bf(a.w);
    r[4] = (short)f2bf(b.x); r[5] = (short)f2bf(b.y); r[6] = (short)f2bf(b.z); r[7] = (short)f2bf(b.w);
    return r;
}

struct KArgs {
    const float *x, *Wq, *bq, *Wk, *bk, *Wv, *bv, *Wo, *bo, *iq;
    const float *sW0, *sb0, *sW1, *sb1;
    unsigned short *kb_bf, *h1_bf, *dp_bf;
    float *vb, *qb, *hret, *pred, *dsil, *warm;
    unsigned *bar;          // 3 one-shot counters, 128B apart, zeroed by host memset
    float *out;
    Coefs cf;
};

// Manual one-shot grid barrier. Counters are zeroed by hipMemsetAsync before
// launch, each counter used exactly once -> no reuse/reset hazard.
// Release: __threadfence + device-scope RMW writes back this XCD's L2.
// Acquire: spin with agent-scope acquire loads invalidates stale L1/L2 lines.
__device__ __forceinline__ void gsync(unsigned* bar, int which) {
    __syncthreads();                       // all block waves drain their stores
    if (threadIdx.x == 0) {
        unsigned* c = bar + which * 32;    // 128B apart
        __threadfence();                   // belt & braces release
        __hip_atomic_fetch_add(c, 1u, __ATOMIC_ACQ_REL, __HIP_MEMORY_SCOPE_AGENT);
        while (__hip_atomic_load(c, __ATOMIC_ACQUIRE, __HIP_MEMORY_SCOPE_AGENT) < GRID_BLKS)
            __builtin_amdgcn_s_sleep(2);
    }
    __syncthreads();
}

// Single fused kernel (plain launch; co-residency by construction:
// __launch_bounds__(256,2) -> 2 blocks/CU, grid 312 <= 512):
//   Phase A: [x;iq]@[Wk|Wv|Wq]^T  (blocks 0..50) + full L3-warm of sW0/sW1/Wo (51..311)
//   Phase B: [kb;q]@sW0^T -> h1/dsil/hret       (blocks 0..59)
//   Phase C: [h1;hret]@sW1^T -> dp/pred         (blocks 0..29)
//   Phase D: epilogue, 624 tiles, 2 per block
__global__ void __launch_bounds__(256, 2) fused(KArgs A) {
    // unioned LDS (phase D only): nW0 branch needs 384*33 bf16 (25344 B) + 8192 + 16384 = 49920 B
    __shared__ __align__(16) unsigned char sbuf[49920];
    const int blk = blockIdx.x, j = threadIdx.x;

    // ---------------- Phase A ----------------
    if (blk < 51) {
        const int wid = j >> 6, L = j & 63;
        const int w = blk * 4 + wid;
        const int lrow = L & 15, kq = (L >> 4) * 8, quad = L >> 4;
        int mf, npair;
        if (w < 192) { mf = w % 8; npair = w / 8; }
        else         { mf = 8;     npair = 24 + (w - 192); }
        const float* Arow = (mf < 8) ? (A.x + (size_t)(mf * 16 + lrow) * CC) : A.iq;
        const int n0 = npair * 32 + lrow, n1 = n0 + 16;
        const float* B0 = (n0 < CC) ? (A.Wk + (size_t)n0 * CC)
                        : (n0 < 2 * CC) ? (A.Wv + (size_t)(n0 - CC) * CC)
                        : (A.Wq + (size_t)(n0 - 2 * CC) * CC);
        const float* B1 = (n1 < CC) ? (A.Wk + (size_t)n1 * CC)
                        : (n1 < 2 * CC) ? (A.Wv + (size_t)(n1 - CC) * CC)
                        : (A.Wq + (size_t)(n1 - 2 * CC) * CC);
        f32x4 acc0 = {0,0,0,0}, acc1 = {0,0,0,0};
        #pragma unroll 2
        for (int s = 0; s < CC / 32; ++s) {
            int k = s * 32 + kq;
            bf16x8 a = ldcvt8(Arow + k);
            bf16x8 b0 = ldcvt8(B0 + k), b1 = ldcvt8(B1 + k);
            acc0 = mfma16(a, b0, acc0); acc1 = mfma16(a, b1, acc1);
        }
        #pragma unroll
        for (int ni = 0; ni < 2; ++ni) {
            f32x4 acc = ni == 0 ? acc0 : acc1;
            int n = npair * 32 + ni * 16 + lrow;
            if (mf < 8) {
                #pragma unroll
                for (int r = 0; r < 4; ++r) {
                    int m = mf * 16 + quad * 4 + r;
                    float v = acc[r];
                    if (n < CC) A.kb_bf[(size_t)m * CC + n] = f2bf(v + A.bk[n]);
                    else        A.vb[(size_t)m * CC + (n - CC)] = v + A.bv[n - CC];
                }
            } else if (quad == 0) {
                A.qb[n - 2 * CC] = acc[0] + A.bq[n - 2 * CC];
            }
        }
    } else {
        // warm path: stream the FULL sW0 + sW1 + Wo (5.3 MB) into L3 for phases B/C/D
        int t = (blk - 51) * 256 + j;   // 261 blocks * 256 threads = 66816 lanes
        float acc = 0.f;
        for (int g = t; g < 331776; g += (GRID_BLKS - 51) * 256) {
            const float4* src; int off;
            if      (g < 147456) { src = (const float4*)A.sW0; off = g; }
            else if (g < 294912) { src = (const float4*)A.sW1; off = g - 147456; }
            else                 { src = (const float4*)A.Wo;  off = g - 294912; }
            float4 v = src[off];
            acc += v.x + v.y + v.z + v.w;
        }
        if (acc != acc) A.warm[0] = acc;   // never taken (finite data); keeps loads live
    }

    gsync(A.bar, 0);

    // ---------------- Phase B ----------------
    if (blk < 60) {
        const int b = blk / 30;
        const int wid = j >> 6, L = j & 63;
        const int w = (blk % 30) * 4 + wid;
        const int mf = w % 5, npair = w / 5;
        const int lrow = L & 15, kq = (L >> 4) * 8, quad = L >> 4;
        const unsigned short* Abf = A.kb_bf + (size_t)(b * TT + mf * 16 + lrow) * CC;
        const int n0 = npair * 32 + lrow;
        const float* B0 = A.sW0 + (size_t)(b * HH + n0) * CC;
        const float* B1 = B0 + 16 * CC;
        f32x4 acc0 = {0,0,0,0}, acc1 = {0,0,0,0};
        if (mf < 4) {
            #pragma unroll 2
            for (int s = 0; s < CC / 32; ++s) {
                int k = s * 32 + kq;
                bf16x8 a = ldbf8(Abf + k);
                bf16x8 b0 = ldcvt8(B0 + k), b1 = ldcvt8(B1 + k);
                acc0 = mfma16(a, b0, acc0); acc1 = mfma16(a, b1, acc1);
            }
        } else {
            #pragma unroll 2
            for (int s = 0; s < CC / 32; ++s) {
                int k = s * 32 + kq;
                bf16x8 a = ldcvt8(A.qb + k);
                bf16x8 b0 = ldcvt8(B0 + k), b1 = ldcvt8(B1 + k);
                acc0 = mfma16(a, b0, acc0); acc1 = mfma16(a, b1, acc1);
            }
        }
        #pragma unroll
        for (int ni = 0; ni < 2; ++ni) {
            f32x4 acc = ni == 0 ? acc0 : acc1;
            int n = npair * 32 + ni * 16 + lrow;
            float bias = A.sb0[b * HH + n];
            if (mf < 4) {
                #pragma unroll
                for (int r = 0; r < 4; ++r) {
                    int t = mf * 16 + quad * 4 + r;
                    float pre = acc[r] + bias;
                    float sig = 1.f / (1.f + expf(-pre));
                    size_t idx = (size_t)(b * TT + t) * HH + n;
                    A.h1_bf[idx] = f2bf(pre * sig);
                    A.dsil[idx]  = sig * (1.f + pre * (1.f - sig));
                }
            } else if (quad == 0) {
                float pre = acc[0] + bias;
                float sig = 1.f / (1.f + expf(-pre));
                A.hret[b * HH + n] = pre * sig;
            }
        }
    }

    gsync(A.bar, 1);

    // ---------------- Phase C ----------------
    if (blk < 30) {
        const int b = blk / 15;
        const int wid = j >> 6, L = j & 63;
        const int w = (blk % 15) * 4 + wid;
        const int mf = w % 5, npair = w / 5;
        const int lrow = L & 15, kq = (L >> 4) * 8, quad = L >> 4;
        const unsigned short* Abf = A.h1_bf + (size_t)(b * TT + mf * 16 + lrow) * HH;
        const float* Aq = A.hret + (size_t)b * HH;
        const int n0 = npair * 32 + lrow;
        const float* B0 = A.sW1 + (size_t)(b * CC + n0) * HH;
        const float* B1 = B0 + 16 * HH;
        f32x4 acc0 = {0,0,0,0}, acc1 = {0,0,0,0};
        if (mf < 4) {
            #pragma unroll 2
            for (int s = 0; s < HH / 32; ++s) {
                int k = s * 32 + kq;
                bf16x8 a = ldbf8(Abf + k);
                bf16x8 b0 = ldcvt8(B0 + k), b1 = ldcvt8(B1 + k);
                acc0 = mfma16(a, b0, acc0); acc1 = mfma16(a, b1, acc1);
            }
        } else {
            #pragma unroll 2
            for (int s = 0; s < HH / 32; ++s) {
                int k = s * 32 + kq;
                bf16x8 a = ldcvt8(Aq + k);
                bf16x8 b0 = ldcvt8(B0 + k), b1 = ldcvt8(B1 + k);
                acc0 = mfma16(a, b0, acc0); acc1 = mfma16(a, b1, acc1);
            }
        }
        #pragma unroll
        for (int ni = 0; ni < 2; ++ni) {
            f32x4 acc = ni == 0 ? acc0 : acc1;
            int n = npair * 32 + ni * 16 + lrow;
            float bias = A.sb1[b * CC + n];
            if (mf < 4) {
                #pragma unroll
                for (int r = 0; r < 4; ++r) {
                    int t = mf * 16 + quad * 4 + r;
                    size_t idx = (size_t)(b * TT + t) * CC + n;
                    A.dp_bf[idx] = f2bf(acc[r] + bias - A.vb[idx]);
                }
            } else if (quad == 0) {
                A.pred[b * CC + n] = acc[0] + bias;
            }
        }
    }

    gsync(A.bar, 2);

    // ---------------- Phase D: epilogue, 624 tiles, 2 per block ----------------
    for (int tile = blk; tile < 624; tile += GRID_BLKS) {
        __syncthreads();   // protect LDS reuse across the two tiles
        if (tile < 288) {                      // nW1 tile
            float* a_t = (float*)sbuf;                 // [64][32]
            float* e_t = (float*)(sbuf + 8192);        // [64][64]
            const int b = tile / 144, rem = tile % 144;
            const int c0 = (rem / 12) * 32, h0 = (rem % 12) * 64;
            for (int i = j; i < TT * 32; i += 256) {
                int t = i >> 5, c = i & 31;
                a_t[t * 32 + c] = A.cf.ct[t] * bf2f(A.dp_bf[((size_t)(b * TT + t)) * CC + c0 + c]);
            }
            for (int i = j; i < TT * 64; i += 256) {
                int t = i >> 6, h = i & 63;
                e_t[t * 64 + h] = bf2f(A.h1_bf[((size_t)(b * TT + t)) * HH + h0 + h]);
            }
            __syncthreads();
            const int ci = j & 31, hb = (j >> 5) * 8;
            float acc[8] = {0, 0, 0, 0, 0, 0, 0, 0};
            for (int t = 0; t < TT; ++t) {
                float av = a_t[t * 32 + ci];
                #pragma unroll
                for (int m = 0; m < 8; ++m) acc[m] += av * e_t[t * 64 + hb + m];
            }
            const size_t idx = ((size_t)b * CC + c0 + ci) * HH + h0 + hb;
            const float4* w4 = (const float4*)(A.sW1 + idx);
            float4 wa = w4[0], wb = w4[1];
            float4 o0, o1;
            o0.x = A.cf.dfac * wa.x - acc[0]; o0.y = A.cf.dfac * wa.y - acc[1];
            o0.z = A.cf.dfac * wa.z - acc[2]; o0.w = A.cf.dfac * wa.w - acc[3];
            o1.x = A.cf.dfac * wb.x - acc[4]; o1.y = A.cf.dfac * wb.y - acc[5];
            o1.z = A.cf.dfac * wb.z - acc[6]; o1.w = A.cf.dfac * wb.w - acc[7];
            *(float4*)(A.out + O_NW1 + idx) = o0;
            *(float4*)(A.out + O_NW1 + idx + 4) = o1;
            if (h0 == 0 && j < 32) {
                float s = 0.f;
                for (int t = 0; t < TT; ++t) s += a_t[t * 32 + j];
                A.out[O_NB1 + b * CC + c0 + j] = A.cf.dfac * A.sb1[b * CC + c0 + j] - s;
            }
        } else if (tile < 576) {               // nW0 tile with inline dh1p (LDS-staged sW1 slice)
            unsigned short* ldsT = (unsigned short*)sbuf;        // [384][33] bf16: [c][hl]
            float* a_t = (float*)(sbuf + 25344);                 // [64][32]
            float* e_t = (float*)(sbuf + 25344 + 8192);          // [64][64]
            const int u = tile - 288;
            const int b = u / 144, rem = u % 144;
            const int h0 = (rem / 6) * 32, c0 = (rem % 6) * 64;
            {
                const int hl = j & 31, cs = j >> 5;               // 8 c-rows per pass
                const float* base = A.sW1 + (size_t)b * CC * HH + h0 + hl;
                for (int c = cs; c < CC; c += 8)
                    ldsT[c * 33 + hl] = f2bf(base[(size_t)c * HH]);
            }
            for (int i = j; i < TT * 64; i += 256) {
                int t = i >> 6, c = i & 63;
                e_t[t * 64 + c] = bf2f(A.kb_bf[((size_t)(b * TT + t)) * CC + c0 + c]);
            }
            __syncthreads();
            const int wid = j >> 6, L = j & 63;
            const int lrow = L & 15, kq = (L >> 4) * 8, quad = L >> 4;
            const unsigned short* Abf = A.dp_bf + (size_t)(b * TT + wid * 16 + lrow) * CC;
            f32x4 acc0 = {0,0,0,0}, acc1 = {0,0,0,0};
            for (int s = 0; s < CC / 32; ++s) {
                int k = s * 32 + kq;
                bf16x8 a = ldbf8(Abf + k);
                bf16x8 b0, b1;
                #pragma unroll
                for (int i = 0; i < 8; ++i) {
                    b0[i] = (short)ldsT[(k + i) * 33 + lrow];
                    b1[i] = (short)ldsT[(k + i) * 33 + 16 + lrow];
                }
                acc0 = mfma16(a, b0, acc0); acc1 = mfma16(a, b1, acc1);
            }
            #pragma unroll
            for (int ni = 0; ni < 2; ++ni) {
                f32x4 acc = ni == 0 ? acc0 : acc1;
                int hl = ni * 16 + lrow;
                #pragma unroll
                for (int r = 0; r < 4; ++r) {
                    int t = wid * 16 + quad * 4 + r;
                    float ds = A.dsil[(size_t)(b * TT + t) * HH + h0 + hl];
                    a_t[t * 32 + hl] = A.cf.ct[t] * (acc[r] * ds);
                }
            }
            __syncthreads();
            const int hi = j & 31, cb = (j >> 5) * 8;
            float acc[8] = {0, 0, 0, 0, 0, 0, 0, 0};
            for (int t = 0; t < TT; ++t) {
                float av = a_t[t * 32 + hi];
                #pragma unroll
                for (int m = 0; m < 8; ++m) acc[m] += av * e_t[t * 64 + cb + m];
            }
            const size_t idx = ((size_t)b * HH + h0 + hi) * CC + c0 + cb;
            const float4* w4 = (const float4*)(A.sW0 + idx);
            float4 wa = w4[0], wb = w4[1];
            float4 o0, o1;
            o0.x = A.cf.dfac * wa.x - acc[0]; o0.y = A.cf.dfac * wa.y - acc[1];
            o0.z = A.cf.dfac * wa.z - acc[2]; o0.w = A.cf.dfac * wa.w - acc[3];
            o1.x = A.cf.dfac * wb.x - acc[4]; o1.y = A.cf.dfac * wb.y - acc[5];
            o1.z = A.cf.dfac * wb.z - acc[6]; o1.w = A.cf.dfac * wb.w - acc[7];
            *(float4*)(A.out + O_NW0 + idx) = o0;
            *(float4*)(A.out + O_NW0 + idx + 4) = o1;
            if (c0 == 0 && j < 32) {
                float s = 0.f;
                for (int t = 0; t < TT; ++t) s += a_t[t * 32 + j];
                A.out[O_NB0 + b * HH + h0 + j] = A.cf.dfac * A.sb0[b * HH + h0 + j] - s;
            }
        } else {                              // out = pred@Wo^T + bo
            float* vecs = (float*)sbuf;
            float* part = (float*)(sbuf + 4096);
            const int rb = tile - 576;
            const int b = rb / 24, nt = rb % 24;
            if (j < CC / 4) ((float4*)vecs)[j] = ((const float4*)(A.pred + b * CC))[j];
            __syncthreads();
            const int nl = j & 15, ks = j >> 4;
            const int n = nt * 16 + nl;
            const float4* wr = (const float4*)(A.Wo + (size_t)n * CC + ks * 24);
            float s = 0.f;
            #pragma unroll
            for (int i = 0; i < 6; ++i) {
                float4 a4 = wr[i];
                const float* v = vecs + ks * 24 + i * 4;
                s += a4.x * v[0] + a4.y * v[1] + a4.z * v[2] + a4.w * v[3];
            }
            part[ks * 17 + nl] = s;
            __syncthreads();
            if (j < 16) {
                int n2 = nt * 16 + j;
                float acc = A.bo[n2];
                #pragma unroll
                for (int kk = 0; kk < 16; ++kk) acc += part[kk * 17 + j];
                A.out[O_OUT + b * CC + n2] = acc;
            }
        }
    }
}

extern "C" void kernel_launch(void* const* d_in, const int* in_sizes, int n_in,
                              void* d_out, int out_size, void* d_ws, size_t ws_size,
                              hipStream_t stream) {
    KArgs a;
    a.x   = (const float*)d_in[0];
    a.Wq  = (const float*)d_in[1];
    a.bq  = (const float*)d_in[2];
    a.Wk  = (const float*)d_in[3];
    a.bk  = (const float*)d_in[4];
    a.Wv  = (const float*)d_in[5];
    a.bv  = (const float*)d_in[6];
    a.Wo  = (const float*)d_in[7];
    a.bo  = (const float*)d_in[8];
    a.iq  = (const float*)d_in[9];
    a.sW0 = (const float*)d_in[10];
    a.sb0 = (const float*)d_in[11];
    a.sW1 = (const float*)d_in[12];
    a.sb1 = (const float*)d_in[13];

    // ws layout: [0,512B) = 3 grid-barrier counters (128B apart), then buffers
    a.bar  = (unsigned*)d_ws;
    float* fw = (float*)d_ws + 128;
    a.qb   = fw;                 // 384
    a.hret = a.qb + 384;         // 1536
    a.pred = a.hret + 1536;      // 768
    a.vb   = a.pred + 768;       // 49152
    a.dsil = a.vb + 49152;       // 98304
    a.warm = a.dsil + 98304;     // 4 (sink, never written in practice)
    unsigned short* us = (unsigned short*)(a.warm + 4);
    a.kb_bf = us;                // 49152
    a.h1_bf = a.kb_bf + 49152;   // 98304
    a.dp_bf = a.h1_bf + 98304;   // 49152

    a.out = (float*)d_out;

    // Closed-form scan coefficients (exact: the clipped seed gate cancels).
    const double mom = 0.9, decay = 1.0 - 0.001, lr = 0.01;
    for (int s = 0; s < TT; ++s) {
        double sum = 0.0;
        for (int t = s; t < TT; ++t) sum += pow(decay, (double)(TT - 1 - t)) * pow(mom, (double)(t - s));
        a.cf.ct[s] = (float)(lr * (1.0 - mom) * sum);
    }
    a.cf.dfac = (float)pow(decay, (double)TT);

    // zero the barrier counters (ws is poisoned between iterations)
    hipMemsetAsync(a.bar, 0, 512, stream);
    fused<<<dim3(GRID_BLKS), dim3(256), 0, stream>>>(a);
}

// Round 3
// 186.293 us; speedup vs baseline: 1.5294x; 1.5294x over previous
//
#include <hip/hip_runtime.h>
#include <hip/hip_bf16.h>
#include <cmath>

#define BB 2
#define TT 64
#define CC 384
#define HH 768

// d_out flat offsets (fp32 elements): out, nW0, nb0, nW1, nb1
#define O_OUT 0
#define O_NW0 768
#define O_NB0 (768 + 589824)
#define O_NW1 (O_NB0 + 1536)
#define O_NB1 (O_NW1 + 589824)

#define GRID_BLKS 312
#define BAR_MAGIC 0x5F3A9D71u

struct Coefs { float ct[TT]; float dfac; };

typedef __attribute__((ext_vector_type(8))) short bf16x8;
typedef __attribute__((ext_vector_type(4))) float f32x4;

__device__ __forceinline__ float bf2f(unsigned short u) {
    union { unsigned int i; float f; } x; x.i = ((unsigned int)u) << 16; return x.f;
}
__device__ __forceinline__ unsigned short f2bf(float f) {
    union { float f; unsigned int i; } u; u.f = f;
    unsigned int x = u.i;
    unsigned int r = (x + 0x7fffu + ((x >> 16) & 1u)) >> 16;  // RNE
    return (unsigned short)r;
}
__device__ __forceinline__ f32x4 mfma16(bf16x8 a, bf16x8 b, f32x4 c) {
    return __builtin_amdgcn_mfma_f32_16x16x32_bf16(a, b, c, 0, 0, 0);
}
__device__ __forceinline__ bf16x8 ldbf8(const unsigned short* p) {
    return *(const bf16x8*)p;
}
__device__ __forceinline__ bf16x8 ldcvt8(const float* p) {
    float4 a = *(const float4*)p, b = *(const float4*)(p + 4);
    bf16x8 r;
    r[0] = (short)f2bf(a.x); r[1] = (short)f2bf(a.y); r[2] = (short)f2bf(a.z); r[3] = (short)f2bf(a.w);
    r[4] = (short)f2bf(b.x); r[5] = (short)f2bf(b.y); r[6] = (short)f2bf(b.z); r[7] = (short)f2bf(b.w);
    return r;
}

struct KArgs {
    const float *x, *Wq, *bq, *Wk, *bk, *Wv, *bv, *Wo, *bo, *iq;
    const float *sW0, *sb0, *sW1, *sb1;
    unsigned short *kb_bf, *h1_bf, *dp_bf;
    float *vb, *qb, *hret, *pred, *dsil, *warm;
    unsigned *bar;   // 7 cache lines: arrive[3] @ word 0/32/64, depart[3] @ 96/128/160, flag @ 192
    float *out;
    Coefs cf;
};

// Cheap one-shot grid barrier, self-cleaning for graph replay.
//  - arrival: RELEASE fetch_add (one L2 writeback per block)
//  - spin: RELAXED agent loads (coherence-point read, NO cache maintenance per poll)
//  - exit: one ACQUIRE fence per block (single invalidate; L3 stays warm)
//  - last leaver (depart counter) resets both words -> next replay starts clean
__device__ __forceinline__ void gsync(unsigned* bar, int which) {
    __syncthreads();
    if (threadIdx.x == 0) {
        unsigned* arr = bar + which * 32;
        unsigned* dep = bar + (3 + which) * 32;
        if (which == 0) {   // wait for block 0's init (fresh/poisoned launch) before first add
            while (__hip_atomic_load(bar + 192, __ATOMIC_RELAXED, __HIP_MEMORY_SCOPE_AGENT) != BAR_MAGIC)
                __builtin_amdgcn_s_sleep(1);
        }
        __hip_atomic_fetch_add(arr, 1u, __ATOMIC_RELEASE, __HIP_MEMORY_SCOPE_AGENT);
        while (__hip_atomic_load(arr, __ATOMIC_RELAXED, __HIP_MEMORY_SCOPE_AGENT) < GRID_BLKS)
            __builtin_amdgcn_s_sleep(4);
        __builtin_amdgcn_fence(__ATOMIC_ACQUIRE, "agent");
        unsigned old = __hip_atomic_fetch_add(dep, 1u, __ATOMIC_RELAXED, __HIP_MEMORY_SCOPE_AGENT);
        if (old == GRID_BLKS - 1) {   // all 312 leaders have passed their spins: safe to reset
            __hip_atomic_store(arr, 0u, __ATOMIC_RELAXED, __HIP_MEMORY_SCOPE_AGENT);
            __hip_atomic_store(dep, 0u, __ATOMIC_RELAXED, __HIP_MEMORY_SCOPE_AGENT);
        }
    }
    __syncthreads();
}

// Single fused kernel (plain launch; co-residency by construction:
// __launch_bounds__(256,2) -> 2 blocks/CU, grid 312 <= 512):
//   Phase A: [x;iq]@[Wk|Wv|Wq]^T  (blocks 0..50) + full L3-warm of sW0/sW1/Wo (51..311)
//   Phase B: [kb;q]@sW0^T -> h1/dsil/hret       (blocks 0..59)
//   Phase C: [h1;hret]@sW1^T -> dp/pred         (blocks 0..29)
//   Phase D: epilogue, 624 tiles, 2 per block
__global__ void __launch_bounds__(256, 2) fused(KArgs A) {
    // unioned LDS (phase D only): nW0 branch needs 384*33 bf16 (25344 B) + 8192 + 16384 = 49920 B
    __shared__ __align__(16) unsigned char sbuf[49920];
    const int blk = blockIdx.x, j = threadIdx.x;

    // barrier state init (gated on magic flag: runs on fresh/poisoned launches,
    // skipped on graph replays where the last-leaver resets left counters at 0)
    if (blk == 0 && j == 0) {
        if (__hip_atomic_load(A.bar + 192, __ATOMIC_RELAXED, __HIP_MEMORY_SCOPE_AGENT) != BAR_MAGIC) {
            #pragma unroll
            for (int i = 0; i < 6; ++i)
                __hip_atomic_store(A.bar + i * 32, 0u, __ATOMIC_RELAXED, __HIP_MEMORY_SCOPE_AGENT);
            __hip_atomic_store(A.bar + 192, BAR_MAGIC, __ATOMIC_RELEASE, __HIP_MEMORY_SCOPE_AGENT);
        }
    }

    // ---------------- Phase A ----------------
    if (blk < 51) {
        const int wid = j >> 6, L = j & 63;
        const int w = blk * 4 + wid;
        const int lrow = L & 15, kq = (L >> 4) * 8, quad = L >> 4;
        int mf, npair;
        if (w < 192) { mf = w % 8; npair = w / 8; }
        else         { mf = 8;     npair = 24 + (w - 192); }
        const float* Arow = (mf < 8) ? (A.x + (size_t)(mf * 16 + lrow) * CC) : A.iq;
        const int n0 = npair * 32 + lrow, n1 = n0 + 16;
        const float* B0 = (n0 < CC) ? (A.Wk + (size_t)n0 * CC)
                        : (n0 < 2 * CC) ? (A.Wv + (size_t)(n0 - CC) * CC)
                        : (A.Wq + (size_t)(n0 - 2 * CC) * CC);
        const float* B1 = (n1 < CC) ? (A.Wk + (size_t)n1 * CC)
                        : (n1 < 2 * CC) ? (A.Wv + (size_t)(n1 - CC) * CC)
                        : (A.Wq + (size_t)(n1 - 2 * CC) * CC);
        f32x4 acc0 = {0,0,0,0}, acc1 = {0,0,0,0};
        #pragma unroll 2
        for (int s = 0; s < CC / 32; ++s) {
            int k = s * 32 + kq;
            bf16x8 a = ldcvt8(Arow + k);
            bf16x8 b0 = ldcvt8(B0 + k), b1 = ldcvt8(B1 + k);
            acc0 = mfma16(a, b0, acc0); acc1 = mfma16(a, b1, acc1);
        }
        #pragma unroll
        for (int ni = 0; ni < 2; ++ni) {
            f32x4 acc = ni == 0 ? acc0 : acc1;
            int n = npair * 32 + ni * 16 + lrow;
            if (mf < 8) {
                #pragma unroll
                for (int r = 0; r < 4; ++r) {
                    int m = mf * 16 + quad * 4 + r;
                    float v = acc[r];
                    if (n < CC) A.kb_bf[(size_t)m * CC + n] = f2bf(v + A.bk[n]);
                    else        A.vb[(size_t)m * CC + (n - CC)] = v + A.bv[n - CC];
                }
            } else if (quad == 0) {
                A.qb[n - 2 * CC] = acc[0] + A.bq[n - 2 * CC];
            }
        }
    } else {
        // warm path: stream the FULL sW0 + sW1 + Wo (5.3 MB) into L3 for phases B/C/D
        int t = (blk - 51) * 256 + j;   // 261 blocks * 256 threads = 66816 lanes
        float acc = 0.f;
        for (int g = t; g < 331776; g += (GRID_BLKS - 51) * 256) {
            const float4* src; int off;
            if      (g < 147456) { src = (const float4*)A.sW0; off = g; }
            else if (g < 294912) { src = (const float4*)A.sW1; off = g - 147456; }
            else                 { src = (const float4*)A.Wo;  off = g - 294912; }
            float4 v = src[off];
            acc += v.x + v.y + v.z + v.w;
        }
        if (acc != acc) A.warm[0] = acc;   // never taken (finite data); keeps loads live
    }

    gsync(A.bar, 0);

    // ---------------- Phase B ----------------
    if (blk < 60) {
        const int b = blk / 30;
        const int wid = j >> 6, L = j & 63;
        const int w = (blk % 30) * 4 + wid;
        const int mf = w % 5, npair = w / 5;
        const int lrow = L & 15, kq = (L >> 4) * 8, quad = L >> 4;
        const unsigned short* Abf = A.kb_bf + (size_t)(b * TT + mf * 16 + lrow) * CC;
        const int n0 = npair * 32 + lrow;
        const float* B0 = A.sW0 + (size_t)(b * HH + n0) * CC;
        const float* B1 = B0 + 16 * CC;
        f32x4 acc0 = {0,0,0,0}, acc1 = {0,0,0,0};
        if (mf < 4) {
            #pragma unroll 2
            for (int s = 0; s < CC / 32; ++s) {
                int k = s * 32 + kq;
                bf16x8 a = ldbf8(Abf + k);
                bf16x8 b0 = ldcvt8(B0 + k), b1 = ldcvt8(B1 + k);
                acc0 = mfma16(a, b0, acc0); acc1 = mfma16(a, b1, acc1);
            }
        } else {
            #pragma unroll 2
            for (int s = 0; s < CC / 32; ++s) {
                int k = s * 32 + kq;
                bf16x8 a = ldcvt8(A.qb + k);
                bf16x8 b0 = ldcvt8(B0 + k), b1 = ldcvt8(B1 + k);
                acc0 = mfma16(a, b0, acc0); acc1 = mfma16(a, b1, acc1);
            }
        }
        #pragma unroll
        for (int ni = 0; ni < 2; ++ni) {
            f32x4 acc = ni == 0 ? acc0 : acc1;
            int n = npair * 32 + ni * 16 + lrow;
            float bias = A.sb0[b * HH + n];
            if (mf < 4) {
                #pragma unroll
                for (int r = 0; r < 4; ++r) {
                    int t = mf * 16 + quad * 4 + r;
                    float pre = acc[r] + bias;
                    float sig = 1.f / (1.f + expf(-pre));
                    size_t idx = (size_t)(b * TT + t) * HH + n;
                    A.h1_bf[idx] = f2bf(pre * sig);
                    A.dsil[idx]  = sig * (1.f + pre * (1.f - sig));
                }
            } else if (quad == 0) {
                float pre = acc[0] + bias;
                float sig = 1.f / (1.f + expf(-pre));
                A.hret[b * HH + n] = pre * sig;
            }
        }
    }

    gsync(A.bar, 1);

    // ---------------- Phase C ----------------
    if (blk < 30) {
        const int b = blk / 15;
        const int wid = j >> 6, L = j & 63;
        const int w = (blk % 15) * 4 + wid;
        const int mf = w % 5, npair = w / 5;
        const int lrow = L & 15, kq = (L >> 4) * 8, quad = L >> 4;
        const unsigned short* Abf = A.h1_bf + (size_t)(b * TT + mf * 16 + lrow) * HH;
        const float* Aq = A.hret + (size_t)b * HH;
        const int n0 = npair * 32 + lrow;
        const float* B0 = A.sW1 + (size_t)(b * CC + n0) * HH;
        const float* B1 = B0 + 16 * HH;
        f32x4 acc0 = {0,0,0,0}, acc1 = {0,0,0,0};
        if (mf < 4) {
            #pragma unroll 2
            for (int s = 0; s < HH / 32; ++s) {
                int k = s * 32 + kq;
                bf16x8 a = ldbf8(Abf + k);
                bf16x8 b0 = ldcvt8(B0 + k), b1 = ldcvt8(B1 + k);
                acc0 = mfma16(a, b0, acc0); acc1 = mfma16(a, b1, acc1);
            }
        } else {
            #pragma unroll 2
            for (int s = 0; s < HH / 32; ++s) {
                int k = s * 32 + kq;
                bf16x8 a = ldcvt8(Aq + k);
                bf16x8 b0 = ldcvt8(B0 + k), b1 = ldcvt8(B1 + k);
                acc0 = mfma16(a, b0, acc0); acc1 = mfma16(a, b1, acc1);
            }
        }
        #pragma unroll
        for (int ni = 0; ni < 2; ++ni) {
            f32x4 acc = ni == 0 ? acc0 : acc1;
            int n = npair * 32 + ni * 16 + lrow;
            float bias = A.sb1[b * CC + n];
            if (mf < 4) {
                #pragma unroll
                for (int r = 0; r < 4; ++r) {
                    int t = mf * 16 + quad * 4 + r;
                    size_t idx = (size_t)(b * TT + t) * CC + n;
                    A.dp_bf[idx] = f2bf(acc[r] + bias - A.vb[idx]);
                }
            } else if (quad == 0) {
                A.pred[b * CC + n] = acc[0] + bias;
            }
        }
    }

    gsync(A.bar, 2);

    // ---------------- Phase D: epilogue, 624 tiles, 2 per block ----------------
    for (int tile = blk; tile < 624; tile += GRID_BLKS) {
        __syncthreads();   // protect LDS reuse across the two tiles
        if (tile < 288) {                      // nW1 tile
            float* a_t = (float*)sbuf;                 // [64][32]
            float* e_t = (float*)(sbuf + 8192);        // [64][64]
            const int b = tile / 144, rem = tile % 144;
            const int c0 = (rem / 12) * 32, h0 = (rem % 12) * 64;
            for (int i = j; i < TT * 32; i += 256) {
                int t = i >> 5, c = i & 31;
                a_t[t * 32 + c] = A.cf.ct[t] * bf2f(A.dp_bf[((size_t)(b * TT + t)) * CC + c0 + c]);
            }
            for (int i = j; i < TT * 64; i += 256) {
                int t = i >> 6, h = i & 63;
                e_t[t * 64 + h] = bf2f(A.h1_bf[((size_t)(b * TT + t)) * HH + h0 + h]);
            }
            __syncthreads();
            const int ci = j & 31, hb = (j >> 5) * 8;
            float acc[8] = {0, 0, 0, 0, 0, 0, 0, 0};
            for (int t = 0; t < TT; ++t) {
                float av = a_t[t * 32 + ci];
                #pragma unroll
                for (int m = 0; m < 8; ++m) acc[m] += av * e_t[t * 64 + hb + m];
            }
            const size_t idx = ((size_t)b * CC + c0 + ci) * HH + h0 + hb;
            const float4* w4 = (const float4*)(A.sW1 + idx);
            float4 wa = w4[0], wb = w4[1];
            float4 o0, o1;
            o0.x = A.cf.dfac * wa.x - acc[0]; o0.y = A.cf.dfac * wa.y - acc[1];
            o0.z = A.cf.dfac * wa.z - acc[2]; o0.w = A.cf.dfac * wa.w - acc[3];
            o1.x = A.cf.dfac * wb.x - acc[4]; o1.y = A.cf.dfac * wb.y - acc[5];
            o1.z = A.cf.dfac * wb.z - acc[6]; o1.w = A.cf.dfac * wb.w - acc[7];
            *(float4*)(A.out + O_NW1 + idx) = o0;
            *(float4*)(A.out + O_NW1 + idx + 4) = o1;
            if (h0 == 0 && j < 32) {
                float s = 0.f;
                for (int t = 0; t < TT; ++t) s += a_t[t * 32 + j];
                A.out[O_NB1 + b * CC + c0 + j] = A.cf.dfac * A.sb1[b * CC + c0 + j] - s;
            }
        } else if (tile < 576) {               // nW0 tile with inline dh1p (LDS-staged sW1 slice)
            unsigned short* ldsT = (unsigned short*)sbuf;        // [384][33] bf16: [c][hl]
            float* a_t = (float*)(sbuf + 25344);                 // [64][32]
            float* e_t = (float*)(sbuf + 25344 + 8192);          // [64][64]
            const int u = tile - 288;
            const int b = u / 144, rem = u % 144;
            const int h0 = (rem / 6) * 32, c0 = (rem % 6) * 64;
            {
                const int hl = j & 31, cs = j >> 5;               // 8 c-rows per pass
                const float* base = A.sW1 + (size_t)b * CC * HH + h0 + hl;
                for (int c = cs; c < CC; c += 8)
                    ldsT[c * 33 + hl] = f2bf(base[(size_t)c * HH]);
            }
            for (int i = j; i < TT * 64; i += 256) {
                int t = i >> 6, c = i & 63;
                e_t[t * 64 + c] = bf2f(A.kb_bf[((size_t)(b * TT + t)) * CC + c0 + c]);
            }
            __syncthreads();
            const int wid = j >> 6, L = j & 63;
            const int lrow = L & 15, kq = (L >> 4) * 8, quad = L >> 4;
            const unsigned short* Abf = A.dp_bf + (size_t)(b * TT + wid * 16 + lrow) * CC;
            f32x4 acc0 = {0,0,0,0}, acc1 = {0,0,0,0};
            for (int s = 0; s < CC / 32; ++s) {
                int k = s * 32 + kq;
                bf16x8 a = ldbf8(Abf + k);
                bf16x8 b0, b1;
                #pragma unroll
                for (int i = 0; i < 8; ++i) {
                    b0[i] = (short)ldsT[(k + i) * 33 + lrow];
                    b1[i] = (short)ldsT[(k + i) * 33 + 16 + lrow];
                }
                acc0 = mfma16(a, b0, acc0); acc1 = mfma16(a, b1, acc1);
            }
            #pragma unroll
            for (int ni = 0; ni < 2; ++ni) {
                f32x4 acc = ni == 0 ? acc0 : acc1;
                int hl = ni * 16 + lrow;
                #pragma unroll
                for (int r = 0; r < 4; ++r) {
                    int t = wid * 16 + quad * 4 + r;
                    float ds = A.dsil[(size_t)(b * TT + t) * HH + h0 + hl];
                    a_t[t * 32 + hl] = A.cf.ct[t] * (acc[r] * ds);
                }
            }
            __syncthreads();
            const int hi = j & 31, cb = (j >> 5) * 8;
            float acc[8] = {0, 0, 0, 0, 0, 0, 0, 0};
            for (int t = 0; t < TT; ++t) {
                float av = a_t[t * 32 + hi];
                #pragma unroll
                for (int m = 0; m < 8; ++m) acc[m] += av * e_t[t * 64 + cb + m];
            }
            const size_t idx = ((size_t)b * HH + h0 + hi) * CC + c0 + cb;
            const float4* w4 = (const float4*)(A.sW0 + idx);
            float4 wa = w4[0], wb = w4[1];
            float4 o0, o1;
            o0.x = A.cf.dfac * wa.x - acc[0]; o0.y = A.cf.dfac * wa.y - acc[1];
            o0.z = A.cf.dfac * wa.z - acc[2]; o0.w = A.cf.dfac * wa.w - acc[3];
            o1.x = A.cf.dfac * wb.x - acc[4]; o1.y = A.cf.dfac * wb.y - acc[5];
            o1.z = A.cf.dfac * wb.z - acc[6]; o1.w = A.cf.dfac * wb.w - acc[7];
            *(float4*)(A.out + O_NW0 + idx) = o0;
            *(float4*)(A.out + O_NW0 + idx + 4) = o1;
            if (c0 == 0 && j < 32) {
                float s = 0.f;
                for (int t = 0; t < TT; ++t) s += a_t[t * 32 + j];
                A.out[O_NB0 + b * HH + h0 + j] = A.cf.dfac * A.sb0[b * HH + h0 + j] - s;
            }
        } else {                              // out = pred@Wo^T + bo
            float* vecs = (float*)sbuf;
            float* part = (float*)(sbuf + 4096);
            const int rb = tile - 576;
            const int b = rb / 24, nt = rb % 24;
            if (j < CC / 4) ((float4*)vecs)[j] = ((const float4*)(A.pred + b * CC))[j];
            __syncthreads();
            const int nl = j & 15, ks = j >> 4;
            const int n = nt * 16 + nl;
            const float4* wr = (const float4*)(A.Wo + (size_t)n * CC + ks * 24);
            float s = 0.f;
            #pragma unroll
            for (int i = 0; i < 6; ++i) {
                float4 a4 = wr[i];
                const float* v = vecs + ks * 24 + i * 4;
                s += a4.x * v[0] + a4.y * v[1] + a4.z * v[2] + a4.w * v[3];
            }
            part[ks * 17 + nl] = s;
            __syncthreads();
            if (j < 16) {
                int n2 = nt * 16 + j;
                float acc = A.bo[n2];
                #pragma unroll
                for (int kk = 0; kk < 16; ++kk) acc += part[kk * 17 + j];
                A.out[O_OUT + b * CC + n2] = acc;
            }
        }
    }
}

extern "C" void kernel_launch(void* const* d_in, const int* in_sizes, int n_in,
                              void* d_out, int out_size, void* d_ws, size_t ws_size,
                              hipStream_t stream) {
    KArgs a;
    a.x   = (const float*)d_in[0];
    a.Wq  = (const float*)d_in[1];
    a.bq  = (const float*)d_in[2];
    a.Wk  = (const float*)d_in[3];
    a.bk  = (const float*)d_in[4];
    a.Wv  = (const float*)d_in[5];
    a.bv  = (const float*)d_in[6];
    a.Wo  = (const float*)d_in[7];
    a.bo  = (const float*)d_in[8];
    a.iq  = (const float*)d_in[9];
    a.sW0 = (const float*)d_in[10];
    a.sb0 = (const float*)d_in[11];
    a.sW1 = (const float*)d_in[12];
    a.sb1 = (const float*)d_in[13];

    // ws layout: [0,1KB) = barrier state (arrive x3, depart x3, flag; one 128B line each)
    a.bar  = (unsigned*)d_ws;
    float* fw = (float*)d_ws + 256;
    a.qb   = fw;                 // 384
    a.hret = a.qb + 384;         // 1536
    a.pred = a.hret + 1536;      // 768
    a.vb   = a.pred + 768;       // 49152
    a.dsil = a.vb + 49152;       // 98304
    a.warm = a.dsil + 98304;     // 4 (sink, never written in practice)
    unsigned short* us = (unsigned short*)(a.warm + 4);
    a.kb_bf = us;                // 49152
    a.h1_bf = a.kb_bf + 49152;   // 98304
    a.dp_bf = a.h1_bf + 98304;   // 49152

    a.out = (float*)d_out;

    // Closed-form scan coefficients (exact: the clipped seed gate cancels).
    const double mom = 0.9, decay = 1.0 - 0.001, lr = 0.01;
    for (int s = 0; s < TT; ++s) {
        double sum = 0.0;
        for (int t = s; t < TT; ++t) sum += pow(decay, (double)(TT - 1 - t)) * pow(mom, (double)(t - s));
        a.cf.ct[s] = (float)(lr * (1.0 - mom) * sum);
    }
    a.cf.dfac = (float)pow(decay, (double)TT);

    fused<<<dim3(GRID_BLKS), dim3(256), 0, stream>>>(a);
}

// Round 4
// 155.942 us; speedup vs baseline: 1.8270x; 1.1946x over previous
//
#include <hip/hip_runtime.h>
#include <hip/hip_bf16.h>
#include <cmath>

#define BB 2
#define TT 64
#define CC 384
#define HH 768

// d_out flat offsets (fp32 elements): out, nW0, nb0, nW1, nb1
#define O_OUT 0
#define O_NW0 768
#define O_NB0 (768 + 589824)
#define O_NW1 (O_NB0 + 1536)
#define O_NB1 (O_NW1 + 589824)

#define GRID_BLKS 312
#define BAR_MAGIC 0x5F3A9D71u
#define AGT __HIP_MEMORY_SCOPE_AGENT

// barrier word offsets (unsigned words into bar)
#define W_ARRX(w, x) (32 + ((w) * 8 + (x)) * 32)   // per-XCD arrive counters, 4 barriers
#define W_WBD(w)     (1056 + (w) * 32)             // writeback-done rendezvous
#define W_DONE(w)    (1184 + (w) * 32)             // invalidate-done (per barrier)
#define W_DEP        1312                          // departures of last barrier
#define W_NJAN       1344                          // number of elected janitors
#define W_CLAIM      1376                          // claim[8], one word per XCD
#define BAR_WORDS    1536                          // 6 KB reserved

struct Coefs { float ct[TT]; float dfac; };

typedef __attribute__((ext_vector_type(8))) short bf16x8;
typedef __attribute__((ext_vector_type(4))) float f32x4;

__device__ __forceinline__ float bf2f(unsigned short u) {
    union { unsigned int i; float f; } x; x.i = ((unsigned int)u) << 16; return x.f;
}
__device__ __forceinline__ unsigned short f2bf(float f) {
    union { float f; unsigned int i; } u; u.f = f;
    unsigned int x = u.i;
    unsigned int r = (x + 0x7fffu + ((x >> 16) & 1u)) >> 16;  // RNE
    return (unsigned short)r;
}
__device__ __forceinline__ f32x4 mfma16(bf16x8 a, bf16x8 b, f32x4 c) {
    return __builtin_amdgcn_mfma_f32_16x16x32_bf16(a, b, c, 0, 0, 0);
}
__device__ __forceinline__ bf16x8 ldbf8(const unsigned short* p) {
    return *(const bf16x8*)p;
}
__device__ __forceinline__ bf16x8 ldcvt8(const float* p) {
    float4 a = *(const float4*)p, b = *(const float4*)(p + 4);
    bf16x8 r;
    r[0] = (short)f2bf(a.x); r[1] = (short)f2bf(a.y); r[2] = (short)f2bf(a.z); r[3] = (short)f2bf(a.w);
    r[4] = (short)f2bf(b.x); r[5] = (short)f2bf(b.y); r[6] = (short)f2bf(b.z); r[7] = (short)f2bf(b.w);
    return r;
}

__device__ __forceinline__ unsigned aload(unsigned* p) {
    return __hip_atomic_load(p, __ATOMIC_RELAXED, AGT);
}
__device__ __forceinline__ void aadd(unsigned* p, unsigned v) {
    __hip_atomic_fetch_add(p, v, __ATOMIC_RELAXED, AGT);
}
__device__ __forceinline__ void astore(unsigned* p, unsigned v) {
    __hip_atomic_store(p, v, __ATOMIC_RELAXED, AGT);
}
__device__ __forceinline__ void bar_reset(unsigned* bar) {
    for (int i = 0; i < 32; ++i) astore(bar + 32 + i * 32, 0u);
    for (int w = 0; w < 4; ++w) { astore(bar + W_WBD(w), 0u); astore(bar + W_DONE(w), 0u); }
    astore(bar + W_DEP, 0u);
    astore(bar + W_NJAN, 0u);
    for (int i = 0; i < 8; ++i) astore(bar + W_CLAIM + i, 0u);
}

struct KArgs {
    const float *x, *Wq, *bq, *Wk, *bk, *Wv, *bv, *Wo, *bo, *iq;
    const float *sW0, *sb0, *sW1, *sb1;
    unsigned short *kb_bf, *h1_bf, *dp_bf;
    float *vb, *qb, *hret, *pred, *dsil, *dh1p, *warm;
    unsigned *bar;
    float *out;
    Coefs cf;
};

// Janitor grid barrier: arrivals are relaxed agent adds to per-XCD lines (no
// cache maintenance); exactly ONE elected block per XCD does the expensive
// agent release fence (buffer_wbl2: flush its XCD's dirty L2 lines to the
// coherence point) and, after ALL janitors' writebacks, the agent acquire
// fence (buffer_inv: drop stale L2 lines). Readers proceed only after their
// own XCD's janitor has invalidated (done counter includes it).
// 64 maintenance ops total vs 1900 in the per-block scheme.
__device__ __forceinline__ void gsync(unsigned* bar, int w, bool jan, int xcc) {
    __syncthreads();   // drains every wave's stores to L2 (vmcnt0 before s_barrier)
    if (threadIdx.x == 0) {
        aadd(bar + W_ARRX(w, xcc), 1u);
        if (jan) {
            for (;;) {                     // wait for all 312 arrivals
                unsigned s = 0;
                #pragma unroll
                for (int x = 0; x < 8; ++x) s += aload(bar + W_ARRX(w, x));
                if (s == GRID_BLKS) break;
                __builtin_amdgcn_s_sleep(2);
            }
            __builtin_amdgcn_fence(__ATOMIC_RELEASE, "agent");   // buffer_wbl2 (my XCD)
            asm volatile("s_waitcnt vmcnt(0)" ::: "memory");      // wbl2 retired
            aadd(bar + W_WBD(w), 1u);
            unsigned nj = aload(bar + W_NJAN);                    // stable: all claims precede arrivals
            while (aload(bar + W_WBD(w)) < nj) __builtin_amdgcn_s_sleep(2);
            __builtin_amdgcn_fence(__ATOMIC_ACQUIRE, "agent");   // buffer_inv (my XCD)
            aadd(bar + W_DONE(w), 1u);
        }
        for (;;) {                         // all leaders: wait until every XCD is invalidated
            unsigned d = aload(bar + W_DONE(w));
            if (d) { unsigned nj = aload(bar + W_NJAN); if (d >= nj) break; }
            __builtin_amdgcn_s_sleep(2);
        }
        if (w == 3) {                      // last barrier: last departer resets for graph replay
            unsigned old = __hip_atomic_fetch_add(bar + W_DEP, 1u, __ATOMIC_RELAXED, AGT);
            if (old == GRID_BLKS - 1) bar_reset(bar);
        }
    }
    __syncthreads();
}

// Single fused kernel, 5 phases / 4 janitor barriers:
//   A : [x;iq]@[Wk|Wv|Wq]^T (blocks 0..50) + L3-warm of sW0/sW1/Wo (51..311)
//   B : [kb;q]@sW0^T -> h1/dsil/hret        (blocks 0..59)
//   C : [h1;hret]@sW1^T -> dp/pred          (blocks 0..29)
//   C2: dh1p = ct*dsil*(dp@sW1) staged ONCE (blocks 0..47) + out=pred@Wo^T+bo (48..95)
//   D : nW1 tiles (0..287) + simplified nW0 tiles (288..575), 2 per block
__global__ void __launch_bounds__(256, 2) fused(KArgs A) {
    __shared__ __align__(16) unsigned char sbuf[49920];
    const int blk = blockIdx.x, j = threadIdx.x;

    // ---- init + janitor election (leader only) ----
    bool jan = false; int xcc = 0;
    if (j == 0) {
        if (blk == 0) {
            if (aload(A.bar) != BAR_MAGIC) {           // fresh / poisoned ws
                bar_reset(A.bar);
                __hip_atomic_store(A.bar, BAR_MAGIC, __ATOMIC_RELEASE, AGT);
            }
        } else {
            while (aload(A.bar) != BAR_MAGIC) __builtin_amdgcn_s_sleep(1);
        }
        asm volatile("s_getreg_b32 %0, hwreg(HW_REG_XCC_ID)" : "=s"(xcc));
        xcc &= 7;
        unsigned prev = atomicCAS(A.bar + W_CLAIM + xcc, 0u, (unsigned)(blk + 1));
        if (prev == 0) {
            jan = true;
            aadd(A.bar + W_NJAN, 1u);
            asm volatile("s_waitcnt vmcnt(0)" ::: "memory");   // njan visible before my arrive
        }
    }

    // ---------------- Phase A ----------------
    if (blk < 51) {
        const int wid = j >> 6, L = j & 63;
        const int w = blk * 4 + wid;
        const int lrow = L & 15, kq = (L >> 4) * 8, quad = L >> 4;
        int mf, npair;
        if (w < 192) { mf = w % 8; npair = w / 8; }
        else         { mf = 8;     npair = 24 + (w - 192); }
        const float* Arow = (mf < 8) ? (A.x + (size_t)(mf * 16 + lrow) * CC) : A.iq;
        const int n0 = npair * 32 + lrow, n1 = n0 + 16;
        const float* B0 = (n0 < CC) ? (A.Wk + (size_t)n0 * CC)
                        : (n0 < 2 * CC) ? (A.Wv + (size_t)(n0 - CC) * CC)
                        : (A.Wq + (size_t)(n0 - 2 * CC) * CC);
        const float* B1 = (n1 < CC) ? (A.Wk + (size_t)n1 * CC)
                        : (n1 < 2 * CC) ? (A.Wv + (size_t)(n1 - CC) * CC)
                        : (A.Wq + (size_t)(n1 - 2 * CC) * CC);
        f32x4 acc0 = {0,0,0,0}, acc1 = {0,0,0,0};
        #pragma unroll 2
        for (int s = 0; s < CC / 32; ++s) {
            int k = s * 32 + kq;
            bf16x8 a = ldcvt8(Arow + k);
            bf16x8 b0 = ldcvt8(B0 + k), b1 = ldcvt8(B1 + k);
            acc0 = mfma16(a, b0, acc0); acc1 = mfma16(a, b1, acc1);
        }
        #pragma unroll
        for (int ni = 0; ni < 2; ++ni) {
            f32x4 acc = ni == 0 ? acc0 : acc1;
            int n = npair * 32 + ni * 16 + lrow;
            if (mf < 8) {
                #pragma unroll
                for (int r = 0; r < 4; ++r) {
                    int m = mf * 16 + quad * 4 + r;
                    float v = acc[r];
                    if (n < CC) A.kb_bf[(size_t)m * CC + n] = f2bf(v + A.bk[n]);
                    else        A.vb[(size_t)m * CC + (n - CC)] = v + A.bv[n - CC];
                }
            } else if (quad == 0) {
                A.qb[n - 2 * CC] = acc[0] + A.bq[n - 2 * CC];
            }
        }
    } else {
        // warm path: stream the FULL sW0 + sW1 + Wo (5.3 MB) into L3 for phases B/C/C2/D
        int t = (blk - 51) * 256 + j;
        float acc = 0.f;
        for (int g = t; g < 331776; g += (GRID_BLKS - 51) * 256) {
            const float4* src; int off;
            if      (g < 147456) { src = (const float4*)A.sW0; off = g; }
            else if (g < 294912) { src = (const float4*)A.sW1; off = g - 147456; }
            else                 { src = (const float4*)A.Wo;  off = g - 294912; }
            float4 v = src[off];
            acc += v.x + v.y + v.z + v.w;
        }
        if (acc != acc) A.warm[0] = acc;   // never taken (finite data); keeps loads live
    }

    gsync(A.bar, 0, jan, xcc);

    // ---------------- Phase B ----------------
    if (blk < 60) {
        const int b = blk / 30;
        const int wid = j >> 6, L = j & 63;
        const int w = (blk % 30) * 4 + wid;
        const int mf = w % 5, npair = w / 5;
        const int lrow = L & 15, kq = (L >> 4) * 8, quad = L >> 4;
        const unsigned short* Abf = A.kb_bf + (size_t)(b * TT + mf * 16 + lrow) * CC;
        const int n0 = npair * 32 + lrow;
        const float* B0 = A.sW0 + (size_t)(b * HH + n0) * CC;
        const float* B1 = B0 + 16 * CC;
        f32x4 acc0 = {0,0,0,0}, acc1 = {0,0,0,0};
        if (mf < 4) {
            #pragma unroll 2
            for (int s = 0; s < CC / 32; ++s) {
                int k = s * 32 + kq;
                bf16x8 a = ldbf8(Abf + k);
                bf16x8 b0 = ldcvt8(B0 + k), b1 = ldcvt8(B1 + k);
                acc0 = mfma16(a, b0, acc0); acc1 = mfma16(a, b1, acc1);
            }
        } else {
            #pragma unroll 2
            for (int s = 0; s < CC / 32; ++s) {
                int k = s * 32 + kq;
                bf16x8 a = ldcvt8(A.qb + k);
                bf16x8 b0 = ldcvt8(B0 + k), b1 = ldcvt8(B1 + k);
                acc0 = mfma16(a, b0, acc0); acc1 = mfma16(a, b1, acc1);
            }
        }
        #pragma unroll
        for (int ni = 0; ni < 2; ++ni) {
            f32x4 acc = ni == 0 ? acc0 : acc1;
            int n = npair * 32 + ni * 16 + lrow;
            float bias = A.sb0[b * HH + n];
            if (mf < 4) {
                #pragma unroll
                for (int r = 0; r < 4; ++r) {
                    int t = mf * 16 + quad * 4 + r;
                    float pre = acc[r] + bias;
                    float sig = 1.f / (1.f + expf(-pre));
                    size_t idx = (size_t)(b * TT + t) * HH + n;
                    A.h1_bf[idx] = f2bf(pre * sig);
                    A.dsil[idx]  = sig * (1.f + pre * (1.f - sig));
                }
            } else if (quad == 0) {
                float pre = acc[0] + bias;
                float sig = 1.f / (1.f + expf(-pre));
                A.hret[b * HH + n] = pre * sig;
            }
        }
    }

    gsync(A.bar, 1, jan, xcc);

    // ---------------- Phase C ----------------
    if (blk < 30) {
        const int b = blk / 15;
        const int wid = j >> 6, L = j & 63;
        const int w = (blk % 15) * 4 + wid;
        const int mf = w % 5, npair = w / 5;
        const int lrow = L & 15, kq = (L >> 4) * 8, quad = L >> 4;
        const unsigned short* Abf = A.h1_bf + (size_t)(b * TT + mf * 16 + lrow) * HH;
        const float* Aq = A.hret + (size_t)b * HH;
        const int n0 = npair * 32 + lrow;
        const float* B0 = A.sW1 + (size_t)(b * CC + n0) * HH;
        const float* B1 = B0 + 16 * HH;
        f32x4 acc0 = {0,0,0,0}, acc1 = {0,0,0,0};
        if (mf < 4) {
            #pragma unroll 2
            for (int s = 0; s < HH / 32; ++s) {
                int k = s * 32 + kq;
                bf16x8 a = ldbf8(Abf + k);
                bf16x8 b0 = ldcvt8(B0 + k), b1 = ldcvt8(B1 + k);
                acc0 = mfma16(a, b0, acc0); acc1 = mfma16(a, b1, acc1);
            }
        } else {
            #pragma unroll 2
            for (int s = 0; s < HH / 32; ++s) {
                int k = s * 32 + kq;
                bf16x8 a = ldcvt8(Aq + k);
                bf16x8 b0 = ldcvt8(B0 + k), b1 = ldcvt8(B1 + k);
                acc0 = mfma16(a, b0, acc0); acc1 = mfma16(a, b1, acc1);
            }
        }
        #pragma unroll
        for (int ni = 0; ni < 2; ++ni) {
            f32x4 acc = ni == 0 ? acc0 : acc1;
            int n = npair * 32 + ni * 16 + lrow;
            float bias = A.sb1[b * CC + n];
            if (mf < 4) {
                #pragma unroll
                for (int r = 0; r < 4; ++r) {
                    int t = mf * 16 + quad * 4 + r;
                    size_t idx = (size_t)(b * TT + t) * CC + n;
                    A.dp_bf[idx] = f2bf(acc[r] + bias - A.vb[idx]);
                }
            } else if (quad == 0) {
                A.pred[b * CC + n] = acc[0] + bias;
            }
        }
    }

    gsync(A.bar, 2, jan, xcc);

    // ---------------- Phase C2: dh1p (once per h-slice) + out ----------------
    if (blk < 48) {
        // dh1p[b,t,h] = ct[t] * dsil[b,t,h] * (dp @ sW1[b,:,h]) for h in [h0,h0+32)
        unsigned short* ldsT = (unsigned short*)sbuf;        // [384][33] bf16: [c][hl]
        const int b = blk / 24, h0 = (blk % 24) * 32;
        {
            const int hl = j & 31, cs = j >> 5;               // 8 c-rows per pass
            const float* base = A.sW1 + (size_t)b * CC * HH + h0 + hl;
            for (int c = cs; c < CC; c += 8)
                ldsT[c * 33 + hl] = f2bf(base[(size_t)c * HH]);
        }
        __syncthreads();
        const int wid = j >> 6, L = j & 63;
        const int lrow = L & 15, kq = (L >> 4) * 8, quad = L >> 4;
        const unsigned short* Abf = A.dp_bf + (size_t)(b * TT + wid * 16 + lrow) * CC;
        f32x4 acc0 = {0,0,0,0}, acc1 = {0,0,0,0};
        for (int s = 0; s < CC / 32; ++s) {
            int k = s * 32 + kq;
            bf16x8 a = ldbf8(Abf + k);
            bf16x8 b0, b1;
            #pragma unroll
            for (int i = 0; i < 8; ++i) {
                b0[i] = (short)ldsT[(k + i) * 33 + lrow];
                b1[i] = (short)ldsT[(k + i) * 33 + 16 + lrow];
            }
            acc0 = mfma16(a, b0, acc0); acc1 = mfma16(a, b1, acc1);
        }
        #pragma unroll
        for (int ni = 0; ni < 2; ++ni) {
            f32x4 acc = ni == 0 ? acc0 : acc1;
            int hl = ni * 16 + lrow;
            #pragma unroll
            for (int r = 0; r < 4; ++r) {
                int t = wid * 16 + quad * 4 + r;
                float ds = A.dsil[(size_t)(b * TT + t) * HH + h0 + hl];
                A.dh1p[(size_t)(b * TT + t) * HH + h0 + hl] = A.cf.ct[t] * (acc[r] * ds);
            }
        }
    } else if (blk < 96) {                // out = pred@Wo^T + bo
        float* vecs = (float*)sbuf;
        float* part = (float*)(sbuf + 4096);
        const int rb = blk - 48;
        const int b = rb / 24, nt = rb % 24;
        if (j < CC / 4) ((float4*)vecs)[j] = ((const float4*)(A.pred + b * CC))[j];
        __syncthreads();
        const int nl = j & 15, ks = j >> 4;
        const int n = nt * 16 + nl;
        const float4* wr = (const float4*)(A.Wo + (size_t)n * CC + ks * 24);
        float s = 0.f;
        #pragma unroll
        for (int i = 0; i < 6; ++i) {
            float4 a4 = wr[i];
            const float* v = vecs + ks * 24 + i * 4;
            s += a4.x * v[0] + a4.y * v[1] + a4.z * v[2] + a4.w * v[3];
        }
        part[ks * 17 + nl] = s;
        __syncthreads();
        if (j < 16) {
            int n2 = nt * 16 + j;
            float acc = A.bo[n2];
            #pragma unroll
            for (int kk = 0; kk < 16; ++kk) acc += part[kk * 17 + j];
            A.out[O_OUT + b * CC + n2] = acc;
        }
    }

    gsync(A.bar, 3, jan, xcc);

    // ---------------- Phase D: 576 weight-update tiles, <=2 per block ----------------
    for (int tile = blk; tile < 576; tile += GRID_BLKS) {
        __syncthreads();   // protect LDS reuse across the two tiles
        if (tile < 288) {                      // nW1 tile
            float* a_t = (float*)sbuf;                 // [64][32]
            float* e_t = (float*)(sbuf + 8192);        // [64][64]
            const int b = tile / 144, rem = tile % 144;
            const int c0 = (rem / 12) * 32, h0 = (rem % 12) * 64;
            for (int i = j; i < TT * 32; i += 256) {
                int t = i >> 5, c = i & 31;
                a_t[t * 32 + c] = A.cf.ct[t] * bf2f(A.dp_bf[((size_t)(b * TT + t)) * CC + c0 + c]);
            }
            for (int i = j; i < TT * 64; i += 256) {
                int t = i >> 6, h = i & 63;
                e_t[t * 64 + h] = bf2f(A.h1_bf[((size_t)(b * TT + t)) * HH + h0 + h]);
            }
            __syncthreads();
            const int ci = j & 31, hb = (j >> 5) * 8;
            float acc[8] = {0, 0, 0, 0, 0, 0, 0, 0};
            for (int t = 0; t < TT; ++t) {
                float av = a_t[t * 32 + ci];
                #pragma unroll
                for (int m = 0; m < 8; ++m) acc[m] += av * e_t[t * 64 + hb + m];
            }
            const size_t idx = ((size_t)b * CC + c0 + ci) * HH + h0 + hb;
            const float4* w4 = (const float4*)(A.sW1 + idx);
            float4 wa = w4[0], wb = w4[1];
            float4 o0, o1;
            o0.x = A.cf.dfac * wa.x - acc[0]; o0.y = A.cf.dfac * wa.y - acc[1];
            o0.z = A.cf.dfac * wa.z - acc[2]; o0.w = A.cf.dfac * wa.w - acc[3];
            o1.x = A.cf.dfac * wb.x - acc[4]; o1.y = A.cf.dfac * wb.y - acc[5];
            o1.z = A.cf.dfac * wb.z - acc[6]; o1.w = A.cf.dfac * wb.w - acc[7];
            *(float4*)(A.out + O_NW1 + idx) = o0;
            *(float4*)(A.out + O_NW1 + idx + 4) = o1;
            if (h0 == 0 && j < 32) {
                float s = 0.f;
                for (int t = 0; t < TT; ++t) s += a_t[t * 32 + j];
                A.out[O_NB1 + b * CC + c0 + j] = A.cf.dfac * A.sb1[b * CC + c0 + j] - s;
            }
        } else {                               // nW0 tile (a_t straight from dh1p)
            float* a_t = (float*)sbuf;                 // [64][32]
            float* e_t = (float*)(sbuf + 8192);        // [64][64]
            const int u = tile - 288;
            const int b = u / 144, rem = u % 144;
            const int h0 = (rem / 6) * 32, c0 = (rem % 6) * 64;
            for (int i = j; i < TT * 32; i += 256) {
                int t = i >> 5, hl = i & 31;
                a_t[t * 32 + hl] = A.dh1p[((size_t)(b * TT + t)) * HH + h0 + hl];
            }
            for (int i = j; i < TT * 64; i += 256) {
                int t = i >> 6, c = i & 63;
                e_t[t * 64 + c] = bf2f(A.kb_bf[((size_t)(b * TT + t)) * CC + c0 + c]);
            }
            __syncthreads();
            const int hi = j & 31, cb = (j >> 5) * 8;
            float acc[8] = {0, 0, 0, 0, 0, 0, 0, 0};
            for (int t = 0; t < TT; ++t) {
                float av = a_t[t * 32 + hi];
                #pragma unroll
                for (int m = 0; m < 8; ++m) acc[m] += av * e_t[t * 64 + cb + m];
            }
            const size_t idx = ((size_t)b * HH + h0 + hi) * CC + c0 + cb;
            const float4* w4 = (const float4*)(A.sW0 + idx);
            float4 wa = w4[0], wb = w4[1];
            float4 o0, o1;
            o0.x = A.cf.dfac * wa.x - acc[0]; o0.y = A.cf.dfac * wa.y - acc[1];
            o0.z = A.cf.dfac * wa.z - acc[2]; o0.w = A.cf.dfac * wa.w - acc[3];
            o1.x = A.cf.dfac * wb.x - acc[4]; o1.y = A.cf.dfac * wb.y - acc[5];
            o1.z = A.cf.dfac * wb.z - acc[6]; o1.w = A.cf.dfac * wb.w - acc[7];
            *(float4*)(A.out + O_NW0 + idx) = o0;
            *(float4*)(A.out + O_NW0 + idx + 4) = o1;
            if (c0 == 0 && j < 32) {
                float s = 0.f;
                for (int t = 0; t < TT; ++t) s += a_t[t * 32 + j];
                A.out[O_NB0 + b * HH + h0 + j] = A.cf.dfac * A.sb0[b * HH + h0 + j] - s;
            }
        }
    }
}

extern "C" void kernel_launch(void* const* d_in, const int* in_sizes, int n_in,
                              void* d_out, int out_size, void* d_ws, size_t ws_size,
                              hipStream_t stream) {
    KArgs a;
    a.x   = (const float*)d_in[0];
    a.Wq  = (const float*)d_in[1];
    a.bq  = (const float*)d_in[2];
    a.Wk  = (const float*)d_in[3];
    a.bk  = (const float*)d_in[4];
    a.Wv  = (const float*)d_in[5];
    a.bv  = (const float*)d_in[6];
    a.Wo  = (const float*)d_in[7];
    a.bo  = (const float*)d_in[8];
    a.iq  = (const float*)d_in[9];
    a.sW0 = (const float*)d_in[10];
    a.sb0 = (const float*)d_in[11];
    a.sW1 = (const float*)d_in[12];
    a.sb1 = (const float*)d_in[13];

    // ws layout: [0, 6KB) barrier state, then fp32 buffers, then bf16 buffers, then dh1p
    a.bar  = (unsigned*)d_ws;
    float* fw = (float*)d_ws + BAR_WORDS;
    a.qb   = fw;                 // 384
    a.hret = a.qb + 384;         // 1536
    a.pred = a.hret + 1536;      // 768
    a.vb   = a.pred + 768;       // 49152
    a.dsil = a.vb + 49152;       // 98304
    a.warm = a.dsil + 98304;     // 4 (sink, never written in practice)
    unsigned short* us = (unsigned short*)(a.warm + 4);
    a.kb_bf = us;                // 49152
    a.h1_bf = a.kb_bf + 49152;   // 98304
    a.dp_bf = a.h1_bf + 98304;   // 49152
    a.dh1p  = (float*)(a.dp_bf + 49152);  // 98304 fp32

    a.out = (float*)d_out;

    // Closed-form scan coefficients (exact: the clipped seed gate cancels).
    const double mom = 0.9, decay = 1.0 - 0.001, lr = 0.01;
    for (int s = 0; s < TT; ++s) {
        double sum = 0.0;
        for (int t = s; t < TT; ++t) sum += pow(decay, (double)(TT - 1 - t)) * pow(mom, (double)(t - s));
        a.cf.ct[s] = (float)(lr * (1.0 - mom) * sum);
    }
    a.cf.dfac = (float)pow(decay, (double)TT);

    fused<<<dim3(GRID_BLKS), dim3(256), 0, stream>>>(a);
}